// Round 1
// baseline (845.511 us; speedup 1.0000x reference)
//
#include <hip/hip_runtime.h>
#include <math.h>

#define Bb 2
#define Nn 2048
#define Ee 256
#define Hh 4
#define DKk 64
#define TN 8
#define TQ 4

// ---------------- QKV projection ----------------
// x:(B,N,E)  Wq/Wk/Wv:(H,E,DK)
// Q:(B,H,N,DK)  KT:(B,H,DK,N)  V:(B,H,N,DK)
__global__ void __launch_bounds__(256) qkv_proj_kernel(
        const float* __restrict__ x,
        const float* __restrict__ Wq,
        const float* __restrict__ Wk,
        const float* __restrict__ Wv,
        float* __restrict__ Q,
        float* __restrict__ KT,
        float* __restrict__ V) {
    __shared__ float xs[TN][Ee];
    int blk = blockIdx.x;                 // B*N/TN = 512
    int b = blk / (Nn / TN);
    int n0 = (blk % (Nn / TN)) * TN;
    int t = threadIdx.x;

    // stage TN rows of x (TN*E = 2048 floats) as float4
    const float4* x4 = (const float4*)(x + ((size_t)b * Nn + n0) * Ee);
    float4* xs4 = (float4*)&xs[0][0];
    xs4[t] = x4[t];
    xs4[t + 256] = x4[t + 256];
    __syncthreads();

    int h = t >> 6;
    int e = t & 63;
    const float* wq = Wq + (size_t)h * Ee * DKk + e;
    const float* wk = Wk + (size_t)h * Ee * DKk + e;
    const float* wv = Wv + (size_t)h * Ee * DKk + e;

    float qa[TN], ka[TN], va[TN];
    #pragma unroll
    for (int r = 0; r < TN; ++r) { qa[r] = 0.f; ka[r] = 0.f; va[r] = 0.f; }

    #pragma unroll 4
    for (int d = 0; d < Ee; ++d) {
        float wqv = wq[(size_t)d * DKk];
        float wkv = wk[(size_t)d * DKk];
        float wvv = wv[(size_t)d * DKk];
        #pragma unroll
        for (int r = 0; r < TN; ++r) {
            float xv = xs[r][d];
            qa[r] += xv * wqv;
            ka[r] += xv * wkv;
            va[r] += xv * wvv;
        }
    }

    size_t bh = (size_t)b * Hh + h;
    #pragma unroll
    for (int r = 0; r < TN; ++r) {
        size_t idx = (bh * Nn + n0 + r) * DKk + e;
        Q[idx] = qa[r];
        V[idx] = va[r];
        KT[(bh * DKk + e) * Nn + n0 + r] = ka[r];
    }
}

// ---------------- fused masked attention (per 4-query tile) ----------------
__global__ void __launch_bounds__(256) attn_kernel(
        const float* __restrict__ Q,
        const float* __restrict__ KT,
        const float* __restrict__ V,
        const int* __restrict__ adj,
        float* __restrict__ heads) {
    __shared__ float sc[TQ][Nn];          // 32 KB score rows
    __shared__ float qs[TQ][DKk];
    __shared__ float red[4][TQ];
    __shared__ float rowmax[TQ], rowinv[TQ];
    __shared__ float oacc[4][TQ][DKk];

    int blk = blockIdx.x;                 // B*H*(N/TQ) = 4096
    int ntile = blk % (Nn / TQ);
    int bh = blk / (Nn / TQ);             // b*H + h
    int h = bh % Hh;
    int b = bh / Hh;
    int n0 = ntile * TQ;
    int t = threadIdx.x;
    int lane = t & 63;
    int wv = t >> 6;

    {
        int i = t >> 6, e = t & 63;
        qs[i][e] = Q[((size_t)bh * Nn + n0 + i) * DKk + e];
    }
    __syncthreads();

    const float scale = 0.125f;           // 1/sqrt(64)
    const float* ktbase = KT + (size_t)bh * DKk * Nn;
    const int* adjbase = adj + ((size_t)b * Nn + n0) * Nn;

    float lmax[TQ];
    #pragma unroll
    for (int i = 0; i < TQ; ++i) lmax[i] = -INFINITY;

    // ---- scores: S = Q K^T (K amortized over TQ rows), mask, store ----
    for (int jm = 0; jm < Nn / (256 * 4); ++jm) {   // 2 iters
        int m4 = jm * 256 + t;                      // float4 column group
        float4 s[TQ];
        #pragma unroll
        for (int i = 0; i < TQ; ++i) s[i] = make_float4(0.f, 0.f, 0.f, 0.f);
        const float4* kt4 = (const float4*)ktbase + m4;
        #pragma unroll 8
        for (int k = 0; k < DKk; ++k) {
            float4 kv = kt4[(size_t)k * (Nn / 4)];
            #pragma unroll
            for (int i = 0; i < TQ; ++i) {
                float qv = qs[i][k];
                s[i].x += qv * kv.x;
                s[i].y += qv * kv.y;
                s[i].z += qv * kv.z;
                s[i].w += qv * kv.w;
            }
        }
        #pragma unroll
        for (int i = 0; i < TQ; ++i) {
            int4 a = ((const int4*)(adjbase + (size_t)i * Nn))[m4];
            float4 sv = s[i];
            sv.x = (a.x > 0) ? sv.x * scale : -INFINITY;
            sv.y = (a.y > 0) ? sv.y * scale : -INFINITY;
            sv.z = (a.z > 0) ? sv.z * scale : -INFINITY;
            sv.w = (a.w > 0) ? sv.w * scale : -INFINITY;
            ((float4*)sc[i])[m4] = sv;
            lmax[i] = fmaxf(lmax[i], fmaxf(fmaxf(sv.x, sv.y), fmaxf(sv.z, sv.w)));
        }
    }

    // ---- row max reduction ----
    #pragma unroll
    for (int i = 0; i < TQ; ++i) {
        float m = lmax[i];
        #pragma unroll
        for (int off = 32; off > 0; off >>= 1) m = fmaxf(m, __shfl_xor(m, off, 64));
        if (lane == 0) red[wv][i] = m;
    }
    __syncthreads();
    if (t < TQ) {
        rowmax[t] = fmaxf(fmaxf(red[0][t], red[1][t]), fmaxf(red[2][t], red[3][t]));
    }
    __syncthreads();

    // ---- exp + row sum ----
    float lsum[TQ];
    #pragma unroll
    for (int i = 0; i < TQ; ++i) lsum[i] = 0.f;
    for (int jm = 0; jm < Nn / (256 * 4); ++jm) {
        int m4 = jm * 256 + t;
        #pragma unroll
        for (int i = 0; i < TQ; ++i) {
            float rm = rowmax[i];
            float4 sv = ((float4*)sc[i])[m4];
            sv.x = __expf(sv.x - rm);
            sv.y = __expf(sv.y - rm);
            sv.z = __expf(sv.z - rm);
            sv.w = __expf(sv.w - rm);
            ((float4*)sc[i])[m4] = sv;
            lsum[i] += sv.x + sv.y + sv.z + sv.w;
        }
    }
    #pragma unroll
    for (int i = 0; i < TQ; ++i) {
        float sm = lsum[i];
        #pragma unroll
        for (int off = 32; off > 0; off >>= 1) sm += __shfl_xor(sm, off, 64);
        if (lane == 0) red[wv][i] = sm;
    }
    __syncthreads();
    if (t < TQ) {
        rowinv[t] = 1.0f / (red[0][t] + red[1][t] + red[2][t] + red[3][t]);
    }
    __syncthreads();

    // ---- PV: out[i][e] = sum_m p[i][m] * V[m][e] ----
    int e = t & 63;
    int g = t >> 6;
    float acc[TQ];
    #pragma unroll
    for (int i = 0; i < TQ; ++i) acc[i] = 0.f;
    const float* vbase = V + (size_t)bh * Nn * DKk + e;
    for (int m = g; m < Nn; m += 4) {
        float vvv = vbase[(size_t)m * DKk];
        #pragma unroll
        for (int i = 0; i < TQ; ++i) acc[i] += sc[i][m] * vvv;
    }
    #pragma unroll
    for (int i = 0; i < TQ; ++i) oacc[g][i][e] = acc[i];
    __syncthreads();
    {
        int i = t >> 6, ee = t & 63;
        float o = (oacc[0][i][ee] + oacc[1][i][ee] + oacc[2][i][ee] + oacc[3][i][ee]) * rowinv[i];
        heads[((size_t)b * Nn + n0 + i) * Ee + h * DKk + ee] = o;
    }
}

// ---------------- output projection: out = heads @ Wo^T + bo ----------------
__global__ void __launch_bounds__(256) outproj_kernel(
        const float* __restrict__ heads,
        const float* __restrict__ Wo,
        const float* __restrict__ bo,
        float* __restrict__ out) {
    __shared__ float hs[Ee];
    int bn = blockIdx.x;                  // B*N = 4096
    int t = threadIdx.x;
    hs[t] = heads[(size_t)bn * Ee + t];
    __syncthreads();
    const float4* w4 = (const float4*)(Wo + (size_t)t * Ee);
    const float4* h4 = (const float4*)hs;
    float acc = 0.f;
    #pragma unroll 8
    for (int d = 0; d < Ee / 4; ++d) {
        float4 w = w4[d];
        float4 hv = h4[d];
        acc += w.x * hv.x + w.y * hv.y + w.z * hv.z + w.w * hv.w;
    }
    out[(size_t)bn * Ee + t] = acc + bo[t];
}

extern "C" void kernel_launch(void* const* d_in, const int* in_sizes, int n_in,
                              void* d_out, int out_size, void* d_ws, size_t ws_size,
                              hipStream_t stream) {
    const float* x  = (const float*)d_in[0];
    const int*   adj = (const int*)d_in[1];
    const float* Wq = (const float*)d_in[2];
    const float* Wk = (const float*)d_in[3];
    const float* Wv = (const float*)d_in[4];
    const float* Wo = (const float*)d_in[5];
    const float* bo = (const float*)d_in[6];
    float* out = (float*)d_out;

    const size_t per = (size_t)Bb * Hh * Nn * DKk;  // 1M floats
    float* Q     = (float*)d_ws;
    float* KT    = Q + per;
    float* V     = KT + per;
    float* heads = V + per;

    qkv_proj_kernel<<<Bb * Nn / TN, 256, 0, stream>>>(x, Wq, Wk, Wv, Q, KT, V);
    attn_kernel<<<Bb * Hh * (Nn / TQ), 256, 0, stream>>>(Q, KT, V, adj, heads);
    outproj_kernel<<<Bb * Nn, 256, 0, stream>>>(heads, Wo, bo, out);
}

// Round 2
// 347.762 us; speedup vs baseline: 2.4313x; 2.4313x over previous
//
#include <hip/hip_runtime.h>
#include <hip/hip_bf16.h>
#include <math.h>

#define Bb 2
#define Nn 2048
#define Ee 256
#define Hh 4
#define DKk 64
#define TN 8

typedef __bf16 bf16x8 __attribute__((ext_vector_type(8)));
typedef float f32x4 __attribute__((ext_vector_type(4)));

// ---------------- adjacency -> bitmask ----------------
// adj: (B,N,N) int32 -> bits: (B,N,N/64) u64, bit j of word w = adj[.., w*64+j] > 0
__global__ void __launch_bounds__(256) pack_adj(const int* __restrict__ adj,
                                                unsigned long long* __restrict__ bits) {
    int t = threadIdx.x;
    size_t base = (size_t)blockIdx.x * 4096;
    #pragma unroll
    for (int it = 0; it < 16; ++it) {
        size_t idx = base + (size_t)it * 256 + t;
        unsigned long long msk = __ballot(adj[idx] > 0);
        if ((t & 63) == 0) bits[idx >> 6] = msk;
    }
}

// ---------------- QKV projection (fp32 compute, bf16 out, all row-major) ----------------
__global__ void __launch_bounds__(256) qkv_proj_kernel(
        const float* __restrict__ x,
        const float* __restrict__ Wq,
        const float* __restrict__ Wk,
        const float* __restrict__ Wv,
        __hip_bfloat16* __restrict__ Q,
        __hip_bfloat16* __restrict__ K,
        __hip_bfloat16* __restrict__ V) {
    __shared__ float xs[TN][Ee];
    int blk = blockIdx.x;                 // B*N/TN = 512
    int b = blk / (Nn / TN);
    int n0 = (blk % (Nn / TN)) * TN;
    int t = threadIdx.x;

    const float4* x4 = (const float4*)(x + ((size_t)b * Nn + n0) * Ee);
    float4* xs4 = (float4*)&xs[0][0];
    xs4[t] = x4[t];
    xs4[t + 256] = x4[t + 256];
    __syncthreads();

    int h = t >> 6;
    int e = t & 63;
    const float* wq = Wq + (size_t)h * Ee * DKk + e;
    const float* wk = Wk + (size_t)h * Ee * DKk + e;
    const float* wv = Wv + (size_t)h * Ee * DKk + e;

    float qa[TN], ka[TN], va[TN];
    #pragma unroll
    for (int r = 0; r < TN; ++r) { qa[r] = 0.f; ka[r] = 0.f; va[r] = 0.f; }

    #pragma unroll 4
    for (int d = 0; d < Ee; ++d) {
        float wqv = wq[(size_t)d * DKk];
        float wkv = wk[(size_t)d * DKk];
        float wvv = wv[(size_t)d * DKk];
        #pragma unroll
        for (int r = 0; r < TN; ++r) {
            float xv = xs[r][d];
            qa[r] += xv * wqv;
            ka[r] += xv * wkv;
            va[r] += xv * wvv;
        }
    }

    size_t bh = (size_t)b * Hh + h;
    #pragma unroll
    for (int r = 0; r < TN; ++r) {
        size_t idx = (bh * Nn + n0 + r) * DKk + e;
        Q[idx] = __float2bfloat16(qa[r]);
        K[idx] = __float2bfloat16(ka[r]);
        V[idx] = __float2bfloat16(va[r]);
    }
}

// ---------------- V (bh,n,dk) -> VT (bh,dk,n) ----------------
__global__ void __launch_bounds__(256) transpose_v(const ushort* __restrict__ V,
                                                   ushort* __restrict__ VT) {
    __shared__ ushort vs[64][72];
    int bh = blockIdx.x >> 5;
    int n0 = (blockIdx.x & 31) << 6;
    int t = threadIdx.x;
    int r = t >> 2, c0 = (t & 3) << 4;
    const uint4* src = (const uint4*)(V + ((size_t)bh * Nn + n0 + r) * DKk + c0);
    uint4 d0 = src[0], d1 = src[1];
    *(uint4*)&vs[r][c0] = d0;
    *(uint4*)&vs[r][c0 + 8] = d1;
    __syncthreads();
    int e = t >> 2, m0 = (t & 3) << 4;
    ushort tmp[16];
    #pragma unroll
    for (int j = 0; j < 16; ++j) tmp[j] = vs[m0 + j][e];
    ushort* dst = VT + ((size_t)bh * DKk + e) * Nn + n0 + m0;
    *(uint4*)dst = *(uint4*)&tmp[0];
    *(uint4*)(dst + 8) = *(uint4*)&tmp[8];
}

// ---------------- flash attention, bf16 MFMA ----------------
// Block: 256 thr = 4 waves. Wave w: queries q0+ (w>>1)*16, key half (w&1).
// Grid: B*H * (N/32) = 512.
__global__ void __launch_bounds__(256, 2) attn_kernel(
        const __bf16* __restrict__ Qb,
        const __bf16* __restrict__ Kb,
        const __bf16* __restrict__ VTb,
        const unsigned long long* __restrict__ bits,
        float* __restrict__ heads) {
    __shared__ __align__(16) __bf16 PS[4][16][72];
    __shared__ float OL[4][16][68];
    __shared__ float mL[4][16], lL[4][16];

    int blk = blockIdx.x;
    int bh = blk >> 6;
    int qt = blk & 63;
    int b = bh >> 2, h = bh & 3;
    int t = threadIdx.x;
    int wid = t >> 6, lane = t & 63, li = lane & 15, quad = lane >> 4;
    int qg = wid >> 1, kh = wid & 1;
    int q0 = qt * 32 + qg * 16;

    const __bf16* qp = Qb + ((size_t)bh * Nn + q0 + li) * DKk + quad * 8;
    bf16x8 qa0 = *(const bf16x8*)qp;
    bf16x8 qa1 = *(const bf16x8*)(qp + 32);

    f32x4 o[4];
    #pragma unroll
    for (int et = 0; et < 4; ++et) o[et] = (f32x4){0.f, 0.f, 0.f, 0.f};
    float m_r[4], l_r[4];
    #pragma unroll
    for (int r = 0; r < 4; ++r) { m_r[r] = -1e30f; l_r[r] = 0.f; }

    const __bf16* Kbase = Kb + (size_t)bh * Nn * DKk;
    const __bf16* VTbase = VTb + (size_t)bh * DKk * Nn;
    const unsigned long long* wbase = bits + ((size_t)b * Nn + q0 + quad * 4) * (Nn / 64);
    const float scale = 0.125f;

    #pragma unroll 1
    for (int kt = 0; kt < 16; ++kt) {
        int m0 = kh * 1024 + kt * 64;

        bf16x8 kb[4][2];
        #pragma unroll
        for (int nt = 0; nt < 4; ++nt) {
            const __bf16* kp = Kbase + (size_t)(m0 + nt * 16 + li) * DKk + quad * 8;
            kb[nt][0] = *(const bf16x8*)kp;
            kb[nt][1] = *(const bf16x8*)(kp + 32);
        }
        bf16x8 vb[4][2];
        #pragma unroll
        for (int et = 0; et < 4; ++et) {
            const __bf16* vp = VTbase + (size_t)(et * 16 + li) * Nn + m0 + quad * 8;
            vb[et][0] = *(const bf16x8*)vp;
            vb[et][1] = *(const bf16x8*)(vp + 32);
        }
        unsigned long long aw[4];
        #pragma unroll
        for (int r = 0; r < 4; ++r) aw[r] = wbase[(size_t)r * (Nn / 64) + (m0 >> 6)];

        f32x4 s[4];
        #pragma unroll
        for (int nt = 0; nt < 4; ++nt) {
            f32x4 z = (f32x4){0.f, 0.f, 0.f, 0.f};
            z = __builtin_amdgcn_mfma_f32_16x16x32_bf16(qa0, kb[nt][0], z, 0, 0, 0);
            s[nt] = __builtin_amdgcn_mfma_f32_16x16x32_bf16(qa1, kb[nt][1], z, 0, 0, 0);
        }

        float al[4];
        #pragma unroll
        for (int r = 0; r < 4; ++r) {
            unsigned long long awr = aw[r];
            float mx = -3e38f;
            #pragma unroll
            for (int nt = 0; nt < 4; ++nt) {
                unsigned grp = (unsigned)(awr >> (nt * 16));
                float v = s[nt][r] * scale;
                v = ((grp >> li) & 1u) ? v : -3e38f;
                s[nt][r] = v;
                mx = fmaxf(mx, v);
            }
            mx = fmaxf(mx, __shfl_xor(mx, 1, 64));
            mx = fmaxf(mx, __shfl_xor(mx, 2, 64));
            mx = fmaxf(mx, __shfl_xor(mx, 4, 64));
            mx = fmaxf(mx, __shfl_xor(mx, 8, 64));
            float mn = fmaxf(m_r[r], mx);
            float alpha = __expf(m_r[r] - mn);
            m_r[r] = mn;
            float ts = 0.f;
            #pragma unroll
            for (int nt = 0; nt < 4; ++nt) {
                float pv = __expf(s[nt][r] - mn);
                s[nt][r] = pv;
                ts += pv;
            }
            ts += __shfl_xor(ts, 1, 64);
            ts += __shfl_xor(ts, 2, 64);
            ts += __shfl_xor(ts, 4, 64);
            ts += __shfl_xor(ts, 8, 64);
            l_r[r] = l_r[r] * alpha + ts;
            al[r] = alpha;
        }

        #pragma unroll
        for (int et = 0; et < 4; ++et) {
            o[et][0] *= al[0];
            o[et][1] *= al[1];
            o[et][2] *= al[2];
            o[et][3] *= al[3];
        }

        #pragma unroll
        for (int nt = 0; nt < 4; ++nt)
            #pragma unroll
            for (int r = 0; r < 4; ++r)
                PS[wid][quad * 4 + r][nt * 16 + li] = (__bf16)s[nt][r];

        bf16x8 pa0 = *(const bf16x8*)&PS[wid][li][quad * 8];
        bf16x8 pa1 = *(const bf16x8*)&PS[wid][li][quad * 8 + 32];

        #pragma unroll
        for (int et = 0; et < 4; ++et) {
            o[et] = __builtin_amdgcn_mfma_f32_16x16x32_bf16(pa0, vb[et][0], o[et], 0, 0, 0);
            o[et] = __builtin_amdgcn_mfma_f32_16x16x32_bf16(pa1, vb[et][1], o[et], 0, 0, 0);
        }
    }

    #pragma unroll
    for (int et = 0; et < 4; ++et)
        #pragma unroll
        for (int r = 0; r < 4; ++r)
            OL[wid][quad * 4 + r][et * 16 + li] = o[et][r];
    if (li == 0) {
        #pragma unroll
        for (int r = 0; r < 4; ++r) {
            mL[wid][quad * 4 + r] = m_r[r];
            lL[wid][quad * 4 + r] = l_r[r];
        }
    }
    __syncthreads();

    // merge the two key-halves per query group, write heads (fp32)
    int q32 = t >> 3;
    int e0 = (t & 7) * 8;
    int g = q32 >> 4, qi = q32 & 15;
    float m1 = mL[2 * g][qi], m2 = mL[2 * g + 1][qi];
    float mm = fmaxf(m1, m2);
    float a1 = __expf(m1 - mm), a2 = __expf(m2 - mm);
    float L = a1 * lL[2 * g][qi] + a2 * lL[2 * g + 1][qi];
    float inv = 1.0f / L;
    const float* o1p = &OL[2 * g][qi][e0];
    const float* o2p = &OL[2 * g + 1][qi][e0];
    float outv[8];
    #pragma unroll
    for (int j = 0; j < 8; ++j) outv[j] = (a1 * o1p[j] + a2 * o2p[j]) * inv;
    float* dst = heads + ((size_t)b * Nn + qt * 32 + q32) * Ee + h * DKk + e0;
    *(float4*)dst = make_float4(outv[0], outv[1], outv[2], outv[3]);
    *(float4*)(dst + 4) = make_float4(outv[4], outv[5], outv[6], outv[7]);
}

// ---------------- output projection: out = heads @ Wo^T + bo ----------------
__global__ void __launch_bounds__(256) outproj_kernel(
        const float* __restrict__ heads,
        const float* __restrict__ Wo,
        const float* __restrict__ bo,
        float* __restrict__ out) {
    __shared__ float hs[Ee];
    int bn = blockIdx.x;                  // B*N = 4096
    int t = threadIdx.x;
    hs[t] = heads[(size_t)bn * Ee + t];
    __syncthreads();
    const float4* w4 = (const float4*)(Wo + (size_t)t * Ee);
    const float4* h4 = (const float4*)hs;
    float acc = 0.f;
    #pragma unroll 8
    for (int d = 0; d < Ee / 4; ++d) {
        float4 w = w4[d];
        float4 hv = h4[d];
        acc += w.x * hv.x + w.y * hv.y + w.z * hv.z + w.w * hv.w;
    }
    out[(size_t)bn * Ee + t] = acc + bo[t];
}

extern "C" void kernel_launch(void* const* d_in, const int* in_sizes, int n_in,
                              void* d_out, int out_size, void* d_ws, size_t ws_size,
                              hipStream_t stream) {
    const float* x   = (const float*)d_in[0];
    const int*   adj = (const int*)d_in[1];
    const float* Wq  = (const float*)d_in[2];
    const float* Wk  = (const float*)d_in[3];
    const float* Wv  = (const float*)d_in[4];
    const float* Wo  = (const float*)d_in[5];
    const float* bo  = (const float*)d_in[6];
    float* out = (float*)d_out;

    char* ws = (char*)d_ws;
    const size_t MB = 1024 * 1024;
    __hip_bfloat16* Qb  = (__hip_bfloat16*)(ws);            // 2 MB
    __hip_bfloat16* Kb  = (__hip_bfloat16*)(ws + 2 * MB);   // 2 MB
    __hip_bfloat16* Vb  = (__hip_bfloat16*)(ws + 4 * MB);   // 2 MB
    __hip_bfloat16* VTb = (__hip_bfloat16*)(ws + 6 * MB);   // 2 MB
    unsigned long long* bits = (unsigned long long*)(ws + 8 * MB);  // 1 MB
    float* heads = (float*)(ws + 9 * MB);                   // 4 MB

    pack_adj<<<2048, 256, 0, stream>>>(adj, bits);
    qkv_proj_kernel<<<Bb * Nn / TN, 256, 0, stream>>>(x, Wq, Wk, Wv, Qb, Kb, Vb);
    transpose_v<<<Bb * Hh * (Nn / 64), 256, 0, stream>>>((const ushort*)Vb, (ushort*)VTb);
    attn_kernel<<<Bb * Hh * (Nn / 32), 256, 0, stream>>>(
        (const __bf16*)Qb, (const __bf16*)Kb, (const __bf16*)VTb, bits, heads);
    outproj_kernel<<<Bb * Nn, 256, 0, stream>>>(heads, Wo, bo, out);
}

// Round 3
// 185.300 us; speedup vs baseline: 4.5629x; 1.8768x over previous
//
#include <hip/hip_runtime.h>
#include <hip/hip_bf16.h>
#include <math.h>

#define Bb 2
#define Nn 2048
#define Ee 256
#define Hh 4
#define DKk 64

typedef __bf16 bf16x8 __attribute__((ext_vector_type(8)));
typedef float f32x4 __attribute__((ext_vector_type(4)));

// ---------------- adjacency -> bitmask ----------------
__global__ void __launch_bounds__(256) pack_adj(const int* __restrict__ adj,
                                                unsigned long long* __restrict__ bits) {
    int t = threadIdx.x;
    size_t base = (size_t)blockIdx.x * 4096;
    #pragma unroll
    for (int it = 0; it < 16; ++it) {
        size_t idx = base + (size_t)it * 256 + t;
        unsigned long long msk = __ballot(adj[idx] > 0);
        if ((t & 63) == 0) bits[idx >> 6] = msk;
    }
}

// ---------------- pack x / weights to bf16 ----------------
// grid = 1024 (xb) + 768 (WB rows) + 64 (WoB)
__global__ void __launch_bounds__(256) pack_all(
        const float* __restrict__ x,
        const float* __restrict__ Wq,
        const float* __restrict__ Wk,
        const float* __restrict__ Wv,
        const float* __restrict__ Wo,
        __bf16* __restrict__ xb,
        __bf16* __restrict__ WB,
        __bf16* __restrict__ WoB) {
    int blk = blockIdx.x, t = threadIdx.x;
    if (blk < 1024) {
        size_t i = ((size_t)blk * 256 + t) * 4;
        float4 v = *(const float4*)(x + i);
        __bf16 o[4] = {(__bf16)v.x, (__bf16)v.y, (__bf16)v.z, (__bf16)v.w};
        *(ushort4*)(xb + i) = *(ushort4*)o;
    } else if (blk < 1024 + 768) {
        int row = blk - 1024;              // (m*4+h)*64 + e
        int m = row >> 8, h = (row >> 6) & 3, e = row & 63;
        const float* W = (m == 0 ? Wq : (m == 1 ? Wk : Wv));
        WB[(size_t)row * 256 + t] = (__bf16)W[h * 16384 + t * 64 + e];
    } else {
        int blk2 = blk - 1792;
        size_t i = ((size_t)blk2 * 256 + t) * 4;
        float4 v = *(const float4*)(Wo + i);
        __bf16 o[4] = {(__bf16)v.x, (__bf16)v.y, (__bf16)v.z, (__bf16)v.w};
        *(ushort4*)(WoB + i) = *(ushort4*)o;
    }
}

// ---------------- QKV projection via MFMA ----------------
// xb:(4096,256) @ WB(768,256)^T -> Q/K/V (bh,n,dk) bf16
__global__ void __launch_bounds__(256) qkv_mfma(
        const __bf16* __restrict__ xb,
        const __bf16* __restrict__ WB,
        __bf16* __restrict__ Qb,
        __bf16* __restrict__ Kb,
        __bf16* __restrict__ Vb) {
    int bm = blockIdx.x;                 // 256 blocks, rows bm*16..+15
    int t = threadIdx.x;
    int wid = t >> 6, lane = t & 63, li = lane & 15, quad = lane >> 4;
    int row0 = bm * 16;

    bf16x8 a[8];
    const __bf16* ap = xb + (size_t)(row0 + li) * 256 + quad * 8;
    #pragma unroll
    for (int i = 0; i < 8; ++i) a[i] = *(const bf16x8*)(ap + i * 32);

    int b = row0 >> 11;
    int nloc = row0 & 2047;

    #pragma unroll 1
    for (int j = 0; j < 12; ++j) {
        int c0 = wid * 192 + j * 16;
        const __bf16* bp = WB + (size_t)(c0 + li) * 256 + quad * 8;
        f32x4 acc = (f32x4){0.f, 0.f, 0.f, 0.f};
        #pragma unroll
        for (int i = 0; i < 8; ++i) {
            bf16x8 bfrag = *(const bf16x8*)(bp + i * 32);
            acc = __builtin_amdgcn_mfma_f32_16x16x32_bf16(a[i], bfrag, acc, 0, 0, 0);
        }
        int c = c0 + li;
        int m = c >> 8, h = (c >> 6) & 3, e = c & 63;
        __bf16* dst = (m == 0 ? Qb : (m == 1 ? Kb : Vb));
        size_t base = (((size_t)(b * 4 + h)) * Nn + nloc + quad * 4) * 64 + e;
        #pragma unroll
        for (int r = 0; r < 4; ++r) dst[base + (size_t)r * 64] = (__bf16)acc[r];
    }
}

// ---------------- V (bh,n,dk) -> VT (bh,dk,n) ----------------
__global__ void __launch_bounds__(256) transpose_v(const ushort* __restrict__ V,
                                                   ushort* __restrict__ VT) {
    __shared__ ushort vs[64][72];
    int bh = blockIdx.x >> 5;
    int n0 = (blockIdx.x & 31) << 6;
    int t = threadIdx.x;
    int r = t >> 2, c0 = (t & 3) << 4;
    const uint4* src = (const uint4*)(V + ((size_t)bh * Nn + n0 + r) * DKk + c0);
    uint4 d0 = src[0], d1 = src[1];
    *(uint4*)&vs[r][c0] = d0;
    *(uint4*)&vs[r][c0 + 8] = d1;
    __syncthreads();
    int e = t >> 2, m0 = (t & 3) << 4;
    ushort tmp[16];
    #pragma unroll
    for (int j = 0; j < 16; ++j) tmp[j] = vs[m0 + j][e];
    ushort* dst = VT + ((size_t)bh * DKk + e) * Nn + n0 + m0;
    *(uint4*)dst = *(uint4*)&tmp[0];
    *(uint4*)(dst + 8) = *(uint4*)&tmp[8];
}

// ---------------- flash attention, bf16 MFMA ----------------
__global__ void __launch_bounds__(256, 2) attn_kernel(
        const __bf16* __restrict__ Qb,
        const __bf16* __restrict__ Kb,
        const __bf16* __restrict__ VTb,
        const unsigned long long* __restrict__ bits,
        __bf16* __restrict__ heads) {
    __shared__ __align__(16) __bf16 PS[4][16][72];
    __shared__ float OL[4][16][68];
    __shared__ float mL[4][16], lL[4][16];

    int blk = blockIdx.x;
    int bh = blk >> 6;
    int qt = blk & 63;
    int b = bh >> 2, h = bh & 3;
    int t = threadIdx.x;
    int wid = t >> 6, lane = t & 63, li = lane & 15, quad = lane >> 4;
    int qg = wid >> 1, kh = wid & 1;
    int q0 = qt * 32 + qg * 16;

    const __bf16* qp = Qb + ((size_t)bh * Nn + q0 + li) * DKk + quad * 8;
    bf16x8 qa0 = *(const bf16x8*)qp;
    bf16x8 qa1 = *(const bf16x8*)(qp + 32);

    f32x4 o[4];
    #pragma unroll
    for (int et = 0; et < 4; ++et) o[et] = (f32x4){0.f, 0.f, 0.f, 0.f};
    float m_r[4], l_r[4];
    #pragma unroll
    for (int r = 0; r < 4; ++r) { m_r[r] = -1e30f; l_r[r] = 0.f; }

    const __bf16* Kbase = Kb + (size_t)bh * Nn * DKk;
    const __bf16* VTbase = VTb + (size_t)bh * DKk * Nn;
    const unsigned long long* wbase = bits + ((size_t)b * Nn + q0 + quad * 4) * (Nn / 64);
    const float scale = 0.125f;

    #pragma unroll 1
    for (int kt = 0; kt < 16; ++kt) {
        int m0 = kh * 1024 + kt * 64;

        bf16x8 kb[4][2];
        #pragma unroll
        for (int nt = 0; nt < 4; ++nt) {
            const __bf16* kp = Kbase + (size_t)(m0 + nt * 16 + li) * DKk + quad * 8;
            kb[nt][0] = *(const bf16x8*)kp;
            kb[nt][1] = *(const bf16x8*)(kp + 32);
        }
        bf16x8 vb[4][2];
        #pragma unroll
        for (int et = 0; et < 4; ++et) {
            const __bf16* vp = VTbase + (size_t)(et * 16 + li) * Nn + m0 + quad * 8;
            vb[et][0] = *(const bf16x8*)vp;
            vb[et][1] = *(const bf16x8*)(vp + 32);
        }
        unsigned long long aw[4];
        #pragma unroll
        for (int r = 0; r < 4; ++r) aw[r] = wbase[(size_t)r * (Nn / 64) + (m0 >> 6)];

        f32x4 s[4];
        #pragma unroll
        for (int nt = 0; nt < 4; ++nt) {
            f32x4 z = (f32x4){0.f, 0.f, 0.f, 0.f};
            z = __builtin_amdgcn_mfma_f32_16x16x32_bf16(qa0, kb[nt][0], z, 0, 0, 0);
            s[nt] = __builtin_amdgcn_mfma_f32_16x16x32_bf16(qa1, kb[nt][1], z, 0, 0, 0);
        }

        float al[4];
        #pragma unroll
        for (int r = 0; r < 4; ++r) {
            unsigned long long awr = aw[r];
            float mx = -3e38f;
            #pragma unroll
            for (int nt = 0; nt < 4; ++nt) {
                unsigned grp = (unsigned)(awr >> (nt * 16));
                float v = s[nt][r] * scale;
                v = ((grp >> li) & 1u) ? v : -3e38f;
                s[nt][r] = v;
                mx = fmaxf(mx, v);
            }
            mx = fmaxf(mx, __shfl_xor(mx, 1, 64));
            mx = fmaxf(mx, __shfl_xor(mx, 2, 64));
            mx = fmaxf(mx, __shfl_xor(mx, 4, 64));
            mx = fmaxf(mx, __shfl_xor(mx, 8, 64));
            float mn = fmaxf(m_r[r], mx);
            float alpha = __expf(m_r[r] - mn);
            m_r[r] = mn;
            float ts = 0.f;
            #pragma unroll
            for (int nt = 0; nt < 4; ++nt) {
                float pv = __expf(s[nt][r] - mn);
                s[nt][r] = pv;
                ts += pv;
            }
            ts += __shfl_xor(ts, 1, 64);
            ts += __shfl_xor(ts, 2, 64);
            ts += __shfl_xor(ts, 4, 64);
            ts += __shfl_xor(ts, 8, 64);
            l_r[r] = l_r[r] * alpha + ts;
            al[r] = alpha;
        }

        #pragma unroll
        for (int et = 0; et < 4; ++et) {
            o[et][0] *= al[0];
            o[et][1] *= al[1];
            o[et][2] *= al[2];
            o[et][3] *= al[3];
        }

        #pragma unroll
        for (int nt = 0; nt < 4; ++nt)
            #pragma unroll
            for (int r = 0; r < 4; ++r)
                PS[wid][quad * 4 + r][nt * 16 + li] = (__bf16)s[nt][r];

        bf16x8 pa0 = *(const bf16x8*)&PS[wid][li][quad * 8];
        bf16x8 pa1 = *(const bf16x8*)&PS[wid][li][quad * 8 + 32];

        #pragma unroll
        for (int et = 0; et < 4; ++et) {
            o[et] = __builtin_amdgcn_mfma_f32_16x16x32_bf16(pa0, vb[et][0], o[et], 0, 0, 0);
            o[et] = __builtin_amdgcn_mfma_f32_16x16x32_bf16(pa1, vb[et][1], o[et], 0, 0, 0);
        }
    }

    #pragma unroll
    for (int et = 0; et < 4; ++et)
        #pragma unroll
        for (int r = 0; r < 4; ++r)
            OL[wid][quad * 4 + r][et * 16 + li] = o[et][r];
    if (li == 0) {
        #pragma unroll
        for (int r = 0; r < 4; ++r) {
            mL[wid][quad * 4 + r] = m_r[r];
            lL[wid][quad * 4 + r] = l_r[r];
        }
    }
    __syncthreads();

    int q32 = t >> 3;
    int e0 = (t & 7) * 8;
    int g = q32 >> 4, qi = q32 & 15;
    float m1 = mL[2 * g][qi], m2 = mL[2 * g + 1][qi];
    float mm = fmaxf(m1, m2);
    float a1 = __expf(m1 - mm), a2 = __expf(m2 - mm);
    float L = a1 * lL[2 * g][qi] + a2 * lL[2 * g + 1][qi];
    float inv = 1.0f / L;
    const float* o1p = &OL[2 * g][qi][e0];
    const float* o2p = &OL[2 * g + 1][qi][e0];
    __bf16 outb[8];
    #pragma unroll
    for (int j = 0; j < 8; ++j) outb[j] = (__bf16)((a1 * o1p[j] + a2 * o2p[j]) * inv);
    __bf16* dst = heads + ((size_t)b * Nn + qt * 32 + q32) * Ee + h * DKk + e0;
    *(uint4*)dst = *(uint4*)outb;
}

// ---------------- output projection via MFMA: out = heads @ Wo^T + bo ----------------
__global__ void __launch_bounds__(256) outproj_mfma(
        const __bf16* __restrict__ hb,
        const __bf16* __restrict__ WoB,
        const float* __restrict__ bo,
        float* __restrict__ out) {
    int bm = blockIdx.x;                 // 256 blocks, rows bm*16..+15
    int t = threadIdx.x;
    int wid = t >> 6, lane = t & 63, li = lane & 15, quad = lane >> 4;
    int row0 = bm * 16;

    bf16x8 a[8];
    const __bf16* ap = hb + (size_t)(row0 + li) * 256 + quad * 8;
    #pragma unroll
    for (int i = 0; i < 8; ++i) a[i] = *(const bf16x8*)(ap + i * 32);

    #pragma unroll 1
    for (int j = 0; j < 4; ++j) {
        int c0 = wid * 64 + j * 16;
        const __bf16* bp = WoB + (size_t)(c0 + li) * 256 + quad * 8;
        f32x4 acc = (f32x4){0.f, 0.f, 0.f, 0.f};
        #pragma unroll
        for (int i = 0; i < 8; ++i) {
            bf16x8 bfrag = *(const bf16x8*)(bp + i * 32);
            acc = __builtin_amdgcn_mfma_f32_16x16x32_bf16(a[i], bfrag, acc, 0, 0, 0);
        }
        int c = c0 + li;
        float bias = bo[c];
        size_t base = ((size_t)row0 + quad * 4) * 256 + c;
        #pragma unroll
        for (int r = 0; r < 4; ++r) out[base + (size_t)r * 256] = acc[r] + bias;
    }
}

extern "C" void kernel_launch(void* const* d_in, const int* in_sizes, int n_in,
                              void* d_out, int out_size, void* d_ws, size_t ws_size,
                              hipStream_t stream) {
    const float* x   = (const float*)d_in[0];
    const int*   adj = (const int*)d_in[1];
    const float* Wq  = (const float*)d_in[2];
    const float* Wk  = (const float*)d_in[3];
    const float* Wv  = (const float*)d_in[4];
    const float* Wo  = (const float*)d_in[5];
    const float* bo  = (const float*)d_in[6];
    float* out = (float*)d_out;

    char* ws = (char*)d_ws;
    const size_t MB = 1024 * 1024;
    __bf16* Qb  = (__bf16*)(ws);                         // 0-2 MB
    __bf16* Kb  = (__bf16*)(ws + 2 * MB);                // 2-4 MB
    __bf16* Vb  = (__bf16*)(ws + 4 * MB);                // 4-6 MB (reused as heads)
    __bf16* VTb = (__bf16*)(ws + 6 * MB);                // 6-8 MB
    unsigned long long* bits = (unsigned long long*)(ws + 8 * MB);  // 8-9 MB
    __bf16* xb  = (__bf16*)(ws + 9 * MB);                // 9-11 MB
    __bf16* WB  = (__bf16*)(ws + 11 * MB);               // 384 KB
    __bf16* WoB = (__bf16*)(ws + 11 * MB + 512 * 1024);  // 128 KB
    __bf16* headsb = Vb;  // safe: stream-ordered, attn no longer reads Vb

    pack_adj<<<2048, 256, 0, stream>>>(adj, bits);
    pack_all<<<1856, 256, 0, stream>>>(x, Wq, Wk, Wv, Wo, xb, WB, WoB);
    qkv_mfma<<<256, 256, 0, stream>>>(xb, WB, Qb, Kb, Vb);
    transpose_v<<<Bb * Hh * (Nn / 64), 256, 0, stream>>>((const ushort*)Vb, (ushort*)VTb);
    attn_kernel<<<Bb * Hh * (Nn / 32), 256, 0, stream>>>(Qb, Kb, VTb, bits, headsb);
    outproj_mfma<<<256, 256, 0, stream>>>(headsb, WoB, bo, out);
}

// Round 4
// 137.239 us; speedup vs baseline: 6.1609x; 1.3502x over previous
//
#include <hip/hip_runtime.h>
#include <hip/hip_bf16.h>
#include <math.h>

#define Bb 2
#define Nn 2048
#define Ee 256
#define Hh 4
#define DKk 64

typedef __bf16 bf16x8 __attribute__((ext_vector_type(8)));
typedef float f32x4 __attribute__((ext_vector_type(4)));

// QSCALE = (1/sqrt(64)) * log2(e): folded into Wq so scores come out of the
// MFMA already in exp2 domain. MOFF folded into MFMA C init (free subtract).
#define QSCALE 0.18033688011112042f
#define MOFF 20.0f

// ---------------- adjacency -> bitmask (int4 + 4x ballot) ----------------
// Group = 256 keys -> 4 u64 words. Word c (c=0..3), bit l <-> key 4*l + c.
// Attn lane li only ever needs word (li&3): bit for key k is word k&3, pos k>>2.
__global__ void __launch_bounds__(256) pack_adj(const int* __restrict__ adj,
                                                unsigned long long* __restrict__ bits) {
    int t = threadIdx.x;
    int wid = t >> 6, lane = t & 63;
    #pragma unroll
    for (int i = 0; i < 4; ++i) {
        int gid = blockIdx.x * 16 + i * 4 + wid;   // 0..32767
        int row = gid >> 3;                        // b*N + q
        int g = gid & 7;                           // 256-key group
        const int4* src = (const int4*)(adj + (size_t)row * Nn + g * 256) + lane;
        int4 v = *src;
        unsigned long long b0 = __ballot(v.x > 0);
        unsigned long long b1 = __ballot(v.y > 0);
        unsigned long long b2 = __ballot(v.z > 0);
        unsigned long long b3 = __ballot(v.w > 0);
        if (lane == 0) {
            ulonglong2* dst = (ulonglong2*)(bits + (size_t)gid * 4);
            ulonglong2 p0; p0.x = b0; p0.y = b1;
            ulonglong2 p1; p1.x = b2; p1.y = b3;
            dst[0] = p0;
            dst[1] = p1;
        }
    }
}

// ---------------- pack x / weights to bf16 (Wq pre-scaled) ----------------
__global__ void __launch_bounds__(256) pack_all(
        const float* __restrict__ x,
        const float* __restrict__ Wq,
        const float* __restrict__ Wk,
        const float* __restrict__ Wv,
        const float* __restrict__ Wo,
        __bf16* __restrict__ xb,
        __bf16* __restrict__ WB,
        __bf16* __restrict__ WoB) {
    int blk = blockIdx.x, t = threadIdx.x;
    if (blk < 1024) {
        size_t i = ((size_t)blk * 256 + t) * 4;
        float4 v = *(const float4*)(x + i);
        __bf16 o[4] = {(__bf16)v.x, (__bf16)v.y, (__bf16)v.z, (__bf16)v.w};
        *(ushort4*)(xb + i) = *(ushort4*)o;
    } else if (blk < 1024 + 768) {
        int row = blk - 1024;              // (m*4+h)*64 + e
        int m = row >> 8, h = (row >> 6) & 3, e = row & 63;
        const float* W = (m == 0 ? Wq : (m == 1 ? Wk : Wv));
        float sc = (m == 0) ? QSCALE : 1.0f;
        WB[(size_t)row * 256 + t] = (__bf16)(W[h * 16384 + t * 64 + e] * sc);
    } else {
        int blk2 = blk - 1792;
        size_t i = ((size_t)blk2 * 256 + t) * 4;
        float4 v = *(const float4*)(Wo + i);
        __bf16 o[4] = {(__bf16)v.x, (__bf16)v.y, (__bf16)v.z, (__bf16)v.w};
        *(ushort4*)(WoB + i) = *(ushort4*)o;
    }
}

// ---------------- QKV projection via MFMA ----------------
// xb:(4096,256) @ WB(768,256)^T. Q -> row-major (bh,n,dk).
// K -> Kf fragment order: unit (bh*128+kt16)*2+chunk, elem (laneB*8+j) holds
//      K[kt16*16 + (laneB&15)][chunk*32 + (laneB>>4)*8 + j].
// V -> Vf fragment order: unit (bh*64+key32)*4+et, elem holds
//      V[key32*32 + (laneB>>4)*8 + j][et*16 + (laneB&15)].
__global__ void __launch_bounds__(256) qkv_mfma(
        const __bf16* __restrict__ xb,
        const __bf16* __restrict__ WB,
        __bf16* __restrict__ Qb,
        __bf16* __restrict__ Kf,
        __bf16* __restrict__ Vf) {
    int bm = blockIdx.x;                 // 256 blocks, rows bm*16..+15
    int t = threadIdx.x;
    int wid = t >> 6, lane = t & 63, li = lane & 15, quad = lane >> 4;
    int row0 = bm * 16;

    bf16x8 a[8];
    const __bf16* ap = xb + (size_t)(row0 + li) * 256 + quad * 8;
    #pragma unroll
    for (int i = 0; i < 8; ++i) a[i] = *(const bf16x8*)(ap + i * 32);

    int b = row0 >> 11;
    int nloc = row0 & 2047;

    #pragma unroll 1
    for (int j = 0; j < 12; ++j) {
        int c0 = wid * 192 + j * 16;
        const __bf16* bp = WB + (size_t)(c0 + li) * 256 + quad * 8;
        f32x4 acc = (f32x4){0.f, 0.f, 0.f, 0.f};
        #pragma unroll
        for (int i = 0; i < 8; ++i) {
            bf16x8 bfrag = *(const bf16x8*)(bp + i * 32);
            acc = __builtin_amdgcn_mfma_f32_16x16x32_bf16(a[i], bfrag, acc, 0, 0, 0);
        }
        int m = c0 >> 8;                  // wave-uniform
        int h = (c0 >> 6) & 3;
        int e0 = c0 & 63;
        int bh = b * 4 + h;
        if (m == 0) {
            size_t base = ((size_t)bh * Nn + nloc + quad * 4) * 64 + e0 + li;
            #pragma unroll
            for (int r = 0; r < 4; ++r) Qb[base + (size_t)r * 64] = (__bf16)acc[r];
        } else if (m == 1) {
            int e = e0 + li;
            int cp = e >> 5, ek = e & 31;
            int qA = ek >> 3, jA = ek & 7;
            int kt = nloc >> 4;
            size_t ub = (((size_t)(bh * 128 + kt)) * 2 + cp) * 512 + qA * 128 + jA;
            #pragma unroll
            for (int r = 0; r < 4; ++r) Kf[ub + (quad * 4 + r) * 8] = (__bf16)acc[r];
        } else {
            int e = e0 + li;
            int et = e >> 4, liA = e & 15;
            int key32 = nloc >> 5;
            int nnb = nloc & 16;
            size_t ub = (((size_t)(bh * 64 + key32)) * 4 + et) * 512 + liA * 8;
            #pragma unroll
            for (int r = 0; r < 4; ++r) {
                int nn = nnb + quad * 4 + r;
                Vf[ub + (nn >> 3) * 128 + (nn & 7)] = (__bf16)acc[r];
            }
        }
    }
}

// ---------------- flash attention: static-max softmax, frag-ordered K/V ----------------
// Grid: bh(8) x qt(128) = 1024 blocks. 4 waves; wave w owns key quarter w.
__global__ void __launch_bounds__(256, 3) attn_kernel(
        const __bf16* __restrict__ Qb,
        const __bf16* __restrict__ Kf,
        const __bf16* __restrict__ Vf,
        const unsigned long long* __restrict__ bits,
        __bf16* __restrict__ heads) {
    __shared__ __align__(16) __bf16 PS[4][16][72];
    __shared__ float OL[4][16][68];
    __shared__ float lL[4][16];

    int blk = blockIdx.x;
    int bh = blk >> 7, qt = blk & 127;
    int b = bh >> 2, h = bh & 3;
    int t = threadIdx.x;
    int wid = t >> 6, lane = t & 63, li = lane & 15, quad = lane >> 4;
    int q0 = qt * 16;

    const __bf16* qp = Qb + ((size_t)bh * Nn + q0 + li) * 64 + quad * 8;
    bf16x8 qa0 = *(const bf16x8*)qp;
    bf16x8 qa1 = *(const bf16x8*)(qp + 32);

    f32x4 o[4];
    #pragma unroll
    for (int et = 0; et < 4; ++et) o[et] = (f32x4){0.f, 0.f, 0.f, 0.f};
    f32x4 ls = (f32x4){0.f, 0.f, 0.f, 0.f};

    const __bf16* Kfb = Kf + (size_t)bh * 131072;
    const __bf16* Vfb = Vf + (size_t)bh * 131072;
    int lanew = lane * 8;

    #pragma unroll 1
    for (int g = 0; g < 2; ++g) {
        int grp = wid * 2 + g;                       // 256-key group 0..7
        unsigned long long aw[4];
        #pragma unroll
        for (int r = 0; r < 4; ++r)
            aw[r] = bits[(((size_t)b * Nn + q0 + quad * 4 + r) * 8 + grp) * 4 + (li & 3)];

        #pragma unroll 1
        for (int tt = 0; tt < 4; ++tt) {
            int key64 = grp * 4 + tt;                // 64-key tile 0..31

            bf16x8 kb[4][2];
            #pragma unroll
            for (int nt = 0; nt < 4; ++nt)
                #pragma unroll
                for (int c = 0; c < 2; ++c)
                    kb[nt][c] = *(const bf16x8*)(Kfb + ((size_t)((key64 * 4 + nt) * 2 + c)) * 512 + lanew);
            bf16x8 vb[4][2];
            #pragma unroll
            for (int et = 0; et < 4; ++et)
                #pragma unroll
                for (int kc = 0; kc < 2; ++kc)
                    vb[et][kc] = *(const bf16x8*)(Vfb + ((size_t)((key64 * 2 + kc) * 4 + et)) * 512 + lanew);

            f32x4 s[4];
            #pragma unroll
            for (int nt = 0; nt < 4; ++nt) {
                f32x4 z = (f32x4){-MOFF, -MOFF, -MOFF, -MOFF};
                z = __builtin_amdgcn_mfma_f32_16x16x32_bf16(qa0, kb[nt][0], z, 0, 0, 0);
                s[nt] = __builtin_amdgcn_mfma_f32_16x16x32_bf16(qa1, kb[nt][1], z, 0, 0, 0);
            }

            int shb = tt * 16 + (li >> 2);
            #pragma unroll
            for (int nt = 0; nt < 4; ++nt) {
                #pragma unroll
                for (int r = 0; r < 4; ++r) {
                    unsigned bit = (unsigned)(aw[r] >> (shb + nt * 4)) & 1u;
                    float p = bit ? __builtin_amdgcn_exp2f(s[nt][r]) : 0.f;
                    ls[r] += p;
                    PS[wid][quad * 4 + r][nt * 16 + li] = (__bf16)p;
                }
            }

            bf16x8 pa0 = *(const bf16x8*)&PS[wid][li][quad * 8];
            bf16x8 pa1 = *(const bf16x8*)&PS[wid][li][quad * 8 + 32];

            #pragma unroll
            for (int et = 0; et < 4; ++et) {
                o[et] = __builtin_amdgcn_mfma_f32_16x16x32_bf16(pa0, vb[et][0], o[et], 0, 0, 0);
                o[et] = __builtin_amdgcn_mfma_f32_16x16x32_bf16(pa1, vb[et][1], o[et], 0, 0, 0);
            }
        }
    }

    // per-wave epilogue: reduce l across the 16 li lanes, stash o + l in LDS
    #pragma unroll
    for (int r = 0; r < 4; ++r) {
        float v = ls[r];
        v += __shfl_xor(v, 1, 64);
        v += __shfl_xor(v, 2, 64);
        v += __shfl_xor(v, 4, 64);
        v += __shfl_xor(v, 8, 64);
        if (li == 0) lL[wid][quad * 4 + r] = v;
        #pragma unroll
        for (int et = 0; et < 4; ++et)
            OL[wid][quad * 4 + r][et * 16 + li] = o[et][r];
    }
    __syncthreads();

    // merge the 4 key quarters: pure sums (static offset shared by all waves)
    int qi = t >> 4, e0 = (t & 15) * 4;
    float l = lL[0][qi] + lL[1][qi] + lL[2][qi] + lL[3][qi];
    float inv = 1.0f / l;
    float s0 = 0.f, s1 = 0.f, s2 = 0.f, s3 = 0.f;
    #pragma unroll
    for (int w = 0; w < 4; ++w) {
        s0 += OL[w][qi][e0];
        s1 += OL[w][qi][e0 + 1];
        s2 += OL[w][qi][e0 + 2];
        s3 += OL[w][qi][e0 + 3];
    }
    __bf16 ob[4] = {(__bf16)(s0 * inv), (__bf16)(s1 * inv),
                    (__bf16)(s2 * inv), (__bf16)(s3 * inv)};
    __bf16* dst = heads + ((size_t)b * Nn + q0 + qi) * 256 + h * 64 + e0;
    *(ushort4*)dst = *(ushort4*)ob;
}

// ---------------- output projection via MFMA: out = heads @ Wo^T + bo ----------------
__global__ void __launch_bounds__(256) outproj_mfma(
        const __bf16* __restrict__ hb,
        const __bf16* __restrict__ WoB,
        const float* __restrict__ bo,
        float* __restrict__ out) {
    int bm = blockIdx.x;                 // 256 blocks, rows bm*16..+15
    int t = threadIdx.x;
    int wid = t >> 6, lane = t & 63, li = lane & 15, quad = lane >> 4;
    int row0 = bm * 16;

    bf16x8 a[8];
    const __bf16* ap = hb + (size_t)(row0 + li) * 256 + quad * 8;
    #pragma unroll
    for (int i = 0; i < 8; ++i) a[i] = *(const bf16x8*)(ap + i * 32);

    #pragma unroll 1
    for (int j = 0; j < 4; ++j) {
        int c0 = wid * 64 + j * 16;
        const __bf16* bp = WoB + (size_t)(c0 + li) * 256 + quad * 8;
        f32x4 acc = (f32x4){0.f, 0.f, 0.f, 0.f};
        #pragma unroll
        for (int i = 0; i < 8; ++i) {
            bf16x8 bfrag = *(const bf16x8*)(bp + i * 32);
            acc = __builtin_amdgcn_mfma_f32_16x16x32_bf16(a[i], bfrag, acc, 0, 0, 0);
        }
        int c = c0 + li;
        float bias = bo[c];
        size_t base = ((size_t)row0 + quad * 4) * 256 + c;
        #pragma unroll
        for (int r = 0; r < 4; ++r) out[base + (size_t)r * 256] = acc[r] + bias;
    }
}

extern "C" void kernel_launch(void* const* d_in, const int* in_sizes, int n_in,
                              void* d_out, int out_size, void* d_ws, size_t ws_size,
                              hipStream_t stream) {
    const float* x   = (const float*)d_in[0];
    const int*   adj = (const int*)d_in[1];
    const float* Wq  = (const float*)d_in[2];
    const float* Wk  = (const float*)d_in[3];
    const float* Wv  = (const float*)d_in[4];
    const float* Wo  = (const float*)d_in[5];
    const float* bo  = (const float*)d_in[6];
    float* out = (float*)d_out;

    char* ws = (char*)d_ws;
    const size_t MB = 1024 * 1024;
    __bf16* Qb  = (__bf16*)(ws);                         // 0-2 MB
    __bf16* Kf  = (__bf16*)(ws + 2 * MB);                // 2-4 MB
    __bf16* Vf  = (__bf16*)(ws + 4 * MB);                // 4-6 MB
    unsigned long long* bits = (unsigned long long*)(ws + 6 * MB);  // 6-7 MB
    __bf16* xb  = (__bf16*)(ws + 7 * MB);                // 7-9 MB (reused as heads)
    __bf16* WB  = (__bf16*)(ws + 9 * MB);                // 384 KB
    __bf16* WoB = (__bf16*)(ws + 9 * MB + 512 * 1024);   // 128 KB
    __bf16* headsb = xb;  // safe: xb only read by qkv_mfma, which precedes attn

    pack_adj<<<2048, 256, 0, stream>>>(adj, bits);
    pack_all<<<1856, 256, 0, stream>>>(x, Wq, Wk, Wv, Wo, xb, WB, WoB);
    qkv_mfma<<<256, 256, 0, stream>>>(xb, WB, Qb, Kf, Vf);
    attn_kernel<<<Bb * Hh * (Nn / 16), 256, 0, stream>>>(Qb, Kf, Vf, bits, headsb);
    outproj_mfma<<<256, 256, 0, stream>>>(headsb, WoB, bo, out);
}